// Round 2
// baseline (463.262 us; speedup 1.0000x reference)
//
#include <hip/hip_runtime.h>
#include <hip/hip_bf16.h>
#include <stdint.h>

typedef unsigned short u16;
typedef __attribute__((ext_vector_type(8))) short short8;
typedef __attribute__((ext_vector_type(4))) float floatx4;

#define NFEAT 256

__device__ __forceinline__ unsigned short f2b(float f) {
    unsigned int x = __builtin_bit_cast(unsigned int, f);
    x += 0x7fffu + ((x >> 16) & 1u);   // round-to-nearest-even
    return (unsigned short)(x >> 16);
}
__device__ __forceinline__ float sigmoidf_(float x) {
    return 1.0f / (1.0f + __expf(-x));
}

// -------- Kernel 1: per-graph attention pooling (fp32 in) -> s[G,256] bf16, pres[G]
// Also converts Wp / W_ih / W_hh / g_feats to bf16 workspace copies for k2a/k2b.
__global__ void __launch_bounds__(256)
k1_attn_pool(const float* __restrict__ nf, const float* __restrict__ gf,
             const int* __restrict__ seg, const float* __restrict__ Wl,
             const float* __restrict__ bl,
             const float* __restrict__ Wp, const float* __restrict__ Wih,
             const float* __restrict__ Whh,
             float* __restrict__ zbuf, u16* __restrict__ s_out,
             float* __restrict__ pres, u16* __restrict__ gfb,
             u16* __restrict__ wpb, u16* __restrict__ wihb, u16* __restrict__ whhb,
             int V)
{
    const int g = blockIdx.x;
    const int t = threadIdx.x;
    __shared__ float red[256];

    // ---- fold-in: bf16 conversion of weights (1M threads cover 458752 elems) ----
    {
        const int n1 = 256 * 256;            // Wp
        const int n2 = n1 + 768 * 256;       // + W_ih
        const int n3 = n2 + 768 * 256;       // + W_hh
        int idx = g * 256 + t;
        if (idx < n3) {
            if (idx < n1)       wpb[idx]       = f2b(Wp[idx]);
            else if (idx < n2)  wihb[idx - n1] = f2b(Wih[idx - n1]);
            else                whhb[idx - n2] = f2b(Whh[idx - n2]);
        }
    }

    // ---- g_feats row g: bf16 copy (raw) + graph-uniform logit part (relu'd) ----
    const float gfv = gf[(size_t)g * NFEAT + t];
    gfb[(size_t)g * NFEAT + t] = f2b(gfv);
    red[t] = fmaxf(gfv, 0.0f) * Wl[t];
    __syncthreads();
    #pragma unroll
    for (int off = 128; off > 0; off >>= 1) {
        if (t < off) red[t] += red[t + off];
        __syncthreads();
    }
    const float gbase = red[0] + bl[0];
    __syncthreads();

    // ---- segment bounds [start, start+count) by binary search on sorted ids ----
    int lo = 0, hi = V;
    while (lo < hi) { int mid = (lo + hi) >> 1; if (seg[mid] < g) lo = mid + 1; else hi = mid; }
    const int start = lo;
    hi = V;
    while (lo < hi) { int mid = (lo + hi) >> 1; if (seg[mid] <= g) lo = mid + 1; else hi = mid; }
    const int count = lo - start;

    const int lane = t & 63;
    const int wv = t >> 6;

    // node-half Wl coefficients, 4 per lane
    const float4 wn = *(const float4*)(Wl + NFEAT + lane * 4);

    // phase 1: z per node (wave-per-node, float4 per lane)
    for (int i = wv; i < count; i += 4) {
        const float4 rv = *(const float4*)(nf + (size_t)(start + i) * NFEAT + lane * 4);
        float d = rv.x * wn.x + rv.y * wn.y + rv.z * wn.z + rv.w * wn.w;
        #pragma unroll
        for (int off = 32; off > 0; off >>= 1) d += __shfl_xor(d, off);
        if (lane == 0) {
            float z = d + gbase;
            zbuf[start + i] = (z > 0.0f) ? z : 0.01f * z;   // leaky_relu 0.01
        }
    }
    __syncthreads();

    // phase 2: softmax over the segment; write a_v back into zbuf
    float m = -3.0e38f;
    for (int i = t; i < count; i += 256) m = fmaxf(m, zbuf[start + i]);
    red[t] = m;
    __syncthreads();
    #pragma unroll
    for (int off = 128; off > 0; off >>= 1) {
        if (t < off) red[t] = fmaxf(red[t], red[t + off]);
        __syncthreads();
    }
    m = red[0];
    __syncthreads();

    float ssum = 0.0f;
    for (int i = t; i < count; i += 256) ssum += __expf(zbuf[start + i] - m);
    red[t] = ssum;
    __syncthreads();
    #pragma unroll
    for (int off = 128; off > 0; off >>= 1) {
        if (t < off) red[t] += red[t + off];
        __syncthreads();
    }
    const float inv = 1.0f / red[0];
    __syncthreads();

    for (int i = t; i < count; i += 256)
        zbuf[start + i] = __expf(zbuf[start + i] - m) * inv;
    __syncthreads();

    // phase 3: s[g,t] = sum_v a_v * nf[v,t]  (thread t owns feature t; rows L2-hot)
    float a0 = 0.f, a1 = 0.f, a2 = 0.f, a3 = 0.f;
    int i = 0;
    for (; i + 3 < count; i += 4) {
        float w0 = zbuf[start + i];
        float w1 = zbuf[start + i + 1];
        float w2 = zbuf[start + i + 2];
        float w3 = zbuf[start + i + 3];
        a0 += w0 * nf[(size_t)(start + i    ) * NFEAT + t];
        a1 += w1 * nf[(size_t)(start + i + 1) * NFEAT + t];
        a2 += w2 * nf[(size_t)(start + i + 2) * NFEAT + t];
        a3 += w3 * nf[(size_t)(start + i + 3) * NFEAT + t];
    }
    for (; i < count; ++i)
        a0 += zbuf[start + i] * nf[(size_t)(start + i) * NFEAT + t];
    s_out[(size_t)g * NFEAT + t] = f2b((a0 + a1) + (a2 + a3));
    if (t == 0) pres[g] = (count > 0) ? 1.0f : 0.0f;
}

// -------- Kernel 2a: context = elu(s @ Wp^T + bp*pres) -> ctx[G,256] bf16 --------
__global__ void __launch_bounds__(256)
k2a_project(const u16* __restrict__ s, const u16* __restrict__ Wpb,
            const float* __restrict__ bp, const float* __restrict__ pres,
            u16* __restrict__ ctx)
{
    const int t = threadIdx.x;
    const int wid = blockIdx.x * 4 + (t >> 6);
    const int lane = t & 63;
    const int m0 = (wid >> 4) * 16;
    const int n0 = (wid & 15) * 16;
    const int lr = lane & 15;
    const int kh = lane >> 4;

    const short* A = (const short*)s   + (size_t)(m0 + lr) * NFEAT + kh * 8;
    const short* B = (const short*)Wpb + (size_t)(n0 + lr) * NFEAT + kh * 8;

    floatx4 acc = {0.f, 0.f, 0.f, 0.f};
    #pragma unroll
    for (int k = 0; k < NFEAT; k += 32) {
        short8 a = *(const short8*)(A + k);
        short8 b = *(const short8*)(B + k);
        acc = __builtin_amdgcn_mfma_f32_16x16x32_bf16(a, b, acc, 0, 0, 0);
    }
    const int col = n0 + lr;                 // C/D: col = lane&15
    const float bias = bp[col];
    const int rbase = m0 + kh * 4;           // C/D: row = (lane>>4)*4 + r
    #pragma unroll
    for (int r = 0; r < 4; ++r) {
        int row = rbase + r;
        float x = acc[r] + bias * pres[row];
        x = (x > 0.0f) ? x : (__expf(x) - 1.0f);   // elu
        ctx[(size_t)row * NFEAT + col] = f2b(x);
    }
}

// -------- Kernel 2b: GRU cell, fused GEMMs + gates -> out[G,256] fp32 --------
__global__ void __launch_bounds__(256)
k2b_gru(const u16* __restrict__ ctx, const u16* __restrict__ gfb,
        const float* __restrict__ gf,
        const u16* __restrict__ Wih, const u16* __restrict__ Whh,
        const float* __restrict__ bih, const float* __restrict__ bhh,
        float* __restrict__ out)
{
    const int t = threadIdx.x;
    const int wid = blockIdx.x * 4 + (t >> 6);
    const int lane = t & 63;
    const int m0 = (wid >> 4) * 16;
    const int j0 = (wid & 15) * 16;
    const int lr = lane & 15;
    const int kh = lane >> 4;

    const short* A1 = (const short*)ctx + (size_t)(m0 + lr) * NFEAT + kh * 8;
    const short* A2 = (const short*)gfb + (size_t)(m0 + lr) * NFEAT + kh * 8;
    const size_t boff = (size_t)(j0 + lr) * NFEAT + kh * 8;
    const short* Bir = (const short*)Wih + boff;
    const short* Biz = Bir + 256 * NFEAT;
    const short* Bin = Bir + 512 * NFEAT;
    const short* Bhr = (const short*)Whh + boff;
    const short* Bhz = Bhr + 256 * NFEAT;
    const short* Bhn = Bhr + 512 * NFEAT;

    floatx4 air = {0,0,0,0}, aiz = {0,0,0,0}, ain = {0,0,0,0};
    floatx4 ahr = {0,0,0,0}, ahz = {0,0,0,0}, ahn = {0,0,0,0};
    #pragma unroll
    for (int k = 0; k < NFEAT; k += 32) {
        short8 a1 = *(const short8*)(A1 + k);
        short8 a2 = *(const short8*)(A2 + k);
        air = __builtin_amdgcn_mfma_f32_16x16x32_bf16(a1, *(const short8*)(Bir + k), air, 0, 0, 0);
        aiz = __builtin_amdgcn_mfma_f32_16x16x32_bf16(a1, *(const short8*)(Biz + k), aiz, 0, 0, 0);
        ain = __builtin_amdgcn_mfma_f32_16x16x32_bf16(a1, *(const short8*)(Bin + k), ain, 0, 0, 0);
        ahr = __builtin_amdgcn_mfma_f32_16x16x32_bf16(a2, *(const short8*)(Bhr + k), ahr, 0, 0, 0);
        ahz = __builtin_amdgcn_mfma_f32_16x16x32_bf16(a2, *(const short8*)(Bhz + k), ahz, 0, 0, 0);
        ahn = __builtin_amdgcn_mfma_f32_16x16x32_bf16(a2, *(const short8*)(Bhn + k), ahn, 0, 0, 0);
    }
    const int col = j0 + lr;
    const float b_ir = bih[col], b_iz = bih[256 + col], b_in = bih[512 + col];
    const float b_hr = bhh[col], b_hz = bhh[256 + col], b_hn = bhh[512 + col];
    const int rbase = m0 + kh * 4;
    #pragma unroll
    for (int r = 0; r < 4; ++r) {
        int row = rbase + r;
        float rg = sigmoidf_((air[r] + b_ir) + (ahr[r] + b_hr));
        float ug = sigmoidf_((aiz[r] + b_iz) + (ahz[r] + b_hz));
        float ng = tanhf((ain[r] + b_in) + rg * (ahn[r] + b_hn));
        float h  = gf[(size_t)row * NFEAT + col];   // fp32 hidden state
        out[(size_t)row * NFEAT + col] = (1.0f - ug) * ng + ug * h;
    }
}

extern "C" void kernel_launch(void* const* d_in, const int* in_sizes, int n_in,
                              void* d_out, int out_size, void* d_ws, size_t ws_size,
                              hipStream_t stream)
{
    const float* nf  = (const float*)d_in[0];   // node_feats [V,256] fp32
    const float* gf  = (const float*)d_in[1];   // g_feats   [G,256] fp32
    const int*   seg = (const int*)d_in[2];     // segment_ids [V], sorted
    const float* Wl  = (const float*)d_in[3];   // [1,512]
    const float* bl  = (const float*)d_in[4];   // [1]
    const float* Wp  = (const float*)d_in[5];   // [256,256]
    const float* bp  = (const float*)d_in[6];   // [256]
    const float* Wih = (const float*)d_in[7];   // [768,256]
    const float* Whh = (const float*)d_in[8];   // [768,256]
    const float* bih = (const float*)d_in[9];   // [768]
    const float* bhh = (const float*)d_in[10];  // [768]

    const int V = in_sizes[2];
    const int G = in_sizes[1] / NFEAT;

    // workspace layout (16B-aligned regions)
    char* ws = (char*)d_ws;
    float* zbuf = (float*)ws;                         ws += (size_t)V * 4;          // 1 MB
    u16*   sbuf = (u16*)ws;                           ws += (size_t)G * NFEAT * 2;  // 2 MB
    u16*   ctx  = (u16*)ws;                           ws += (size_t)G * NFEAT * 2;  // 2 MB
    u16*   gfb  = (u16*)ws;                           ws += (size_t)G * NFEAT * 2;  // 2 MB
    u16*   wpb  = (u16*)ws;                           ws += (size_t)256 * 256 * 2;  // 128 KB
    u16*   wihb = (u16*)ws;                           ws += (size_t)768 * 256 * 2;  // 384 KB
    u16*   whhb = (u16*)ws;                           ws += (size_t)768 * 256 * 2;  // 384 KB
    float* pres = (float*)ws;                         ws += (size_t)G * 4;          // 16 KB

    k1_attn_pool<<<G, 256, 0, stream>>>(nf, gf, seg, Wl, bl, Wp, Wih, Whh,
                                        zbuf, sbuf, pres, gfb, wpb, wihb, whhb, V);
    k2a_project<<<G / 4, 256, 0, stream>>>(sbuf, wpb, bp, pres, ctx);
    k2b_gru<<<G / 4, 256, 0, stream>>>(ctx, gfb, gf, wihb, whhb, bih, bhh, (float*)d_out);
    (void)ws_size; (void)n_in; (void)out_size;
}

// Round 3
// 438.099 us; speedup vs baseline: 1.0574x; 1.0574x over previous
//
#include <hip/hip_runtime.h>
#include <hip/hip_bf16.h>
#include <stdint.h>

typedef unsigned short u16;
typedef __attribute__((ext_vector_type(8))) short short8;
typedef __attribute__((ext_vector_type(4))) float floatx4;

#define NFEAT 256

__device__ __forceinline__ unsigned short f2b(float f) {
    unsigned int x = __builtin_bit_cast(unsigned int, f);
    x += 0x7fffu + ((x >> 16) & 1u);   // round-to-nearest-even
    return (unsigned short)(x >> 16);
}
__device__ __forceinline__ float sigmoidf_(float x) {
    return 1.0f / (1.0f + __expf(-x));
}

// -------- Kernel 1: single-pass online-softmax attention pooling --------
// fp32 in -> s[G,256] bf16, pres[G]. Each wave keeps running (m, l, acc[4/lane]);
// node rows are read ONCE (phase-1 logit dot and weighted accumulation fused).
// Also converts Wp / W_ih / W_hh / g_feats to bf16 workspace copies for k2a/k2b.
__global__ void __launch_bounds__(256)
k1_attn_pool(const float* __restrict__ nf, const float* __restrict__ gf,
             const int* __restrict__ seg, const float* __restrict__ Wl,
             const float* __restrict__ bl,
             const float* __restrict__ Wp, const float* __restrict__ Wih,
             const float* __restrict__ Whh,
             u16* __restrict__ s_out,
             float* __restrict__ pres, u16* __restrict__ gfb,
             u16* __restrict__ wpb, u16* __restrict__ wihb, u16* __restrict__ whhb,
             int V)
{
    const int g = blockIdx.x;
    const int t = threadIdx.x;
    __shared__ float red[256];
    __shared__ float accs[4][256];
    __shared__ float mws[4], lws[4];

    // ---- fold-in: bf16 conversion of weights (1M threads cover 458752 elems) ----
    {
        const int n1 = 256 * 256;            // Wp
        const int n2 = n1 + 768 * 256;       // + W_ih
        const int n3 = n2 + 768 * 256;       // + W_hh
        int idx = g * 256 + t;
        if (idx < n3) {
            if (idx < n1)       wpb[idx]       = f2b(Wp[idx]);
            else if (idx < n2)  wihb[idx - n1] = f2b(Wih[idx - n1]);
            else                whhb[idx - n2] = f2b(Whh[idx - n2]);
        }
    }

    // ---- g_feats row g: bf16 copy (raw) + graph-uniform logit part (relu'd) ----
    const float gfv = gf[(size_t)g * NFEAT + t];
    gfb[(size_t)g * NFEAT + t] = f2b(gfv);
    red[t] = fmaxf(gfv, 0.0f) * Wl[t];
    __syncthreads();
    #pragma unroll
    for (int off = 128; off > 0; off >>= 1) {
        if (t < off) red[t] += red[t + off];
        __syncthreads();
    }
    const float gbase = red[0] + bl[0];
    __syncthreads();

    // ---- segment bounds [start, start+count) by binary search on sorted ids ----
    int lo = 0, hi = V;
    while (lo < hi) { int mid = (lo + hi) >> 1; if (seg[mid] < g) lo = mid + 1; else hi = mid; }
    const int start = lo;
    hi = V;
    while (lo < hi) { int mid = (lo + hi) >> 1; if (seg[mid] <= g) lo = mid + 1; else hi = mid; }
    const int count = lo - start;

    const int lane = t & 63;
    const int wv = t >> 6;

    // node-half Wl coefficients, 4 per lane
    const float4 wn = *(const float4*)(Wl + NFEAT + lane * 4);

    // ---- single pass: online softmax + weighted feature accumulation ----
    float m = -3.0e38f, l = 0.0f;
    float4 acc = {0.f, 0.f, 0.f, 0.f};
    const float* base = nf + (size_t)start * NFEAT + lane * 4;

    float4 x = {0.f, 0.f, 0.f, 0.f};
    if (wv < count) x = *(const float4*)(base + (size_t)wv * NFEAT);
    for (int i = wv; i < count; i += 4) {
        float4 nx = {0.f, 0.f, 0.f, 0.f};
        if (i + 4 < count) nx = *(const float4*)(base + (size_t)(i + 4) * NFEAT);
        float d = x.x * wn.x + x.y * wn.y + x.z * wn.z + x.w * wn.w;
        #pragma unroll
        for (int off = 32; off > 0; off >>= 1) d += __shfl_xor(d, off);
        float z = d + gbase;
        z = (z > 0.0f) ? z : 0.01f * z;          // leaky_relu 0.01
        float mn = fmaxf(m, z);
        float c = __expf(m - mn);
        float p = __expf(z - mn);
        l = l * c + p;
        acc.x = acc.x * c + p * x.x;
        acc.y = acc.y * c + p * x.y;
        acc.z = acc.z * c + p * x.z;
        acc.w = acc.w * c + p * x.w;
        m = mn;
        x = nx;
    }

    // ---- merge the 4 waves' (m, l, acc) ----
    accs[wv][lane * 4 + 0] = acc.x;
    accs[wv][lane * 4 + 1] = acc.y;
    accs[wv][lane * 4 + 2] = acc.z;
    accs[wv][lane * 4 + 3] = acc.w;
    if (lane == 0) { mws[wv] = m; lws[wv] = l; }
    __syncthreads();

    const float M = fmaxf(fmaxf(mws[0], mws[1]), fmaxf(mws[2], mws[3]));
    const float c0 = __expf(mws[0] - M), c1 = __expf(mws[1] - M);
    const float c2 = __expf(mws[2] - M), c3 = __expf(mws[3] - M);
    const float L = lws[0] * c0 + lws[1] * c1 + lws[2] * c2 + lws[3] * c3;
    const float sv = accs[0][t] * c0 + accs[1][t] * c1 + accs[2][t] * c2 + accs[3][t] * c3;
    const float inv = (L > 0.0f) ? 1.0f / L : 0.0f;   // count==0 -> s=0
    s_out[(size_t)g * NFEAT + t] = f2b(sv * inv);
    if (t == 0) pres[g] = (count > 0) ? 1.0f : 0.0f;
}

// -------- Kernel 2a: context = elu(s @ Wp^T + bp*pres) -> ctx[G,256] bf16 --------
__global__ void __launch_bounds__(256)
k2a_project(const u16* __restrict__ s, const u16* __restrict__ Wpb,
            const float* __restrict__ bp, const float* __restrict__ pres,
            u16* __restrict__ ctx)
{
    const int t = threadIdx.x;
    const int wid = blockIdx.x * 4 + (t >> 6);
    const int lane = t & 63;
    const int m0 = (wid >> 4) * 16;
    const int n0 = (wid & 15) * 16;
    const int lr = lane & 15;
    const int kh = lane >> 4;

    const short* A = (const short*)s   + (size_t)(m0 + lr) * NFEAT + kh * 8;
    const short* B = (const short*)Wpb + (size_t)(n0 + lr) * NFEAT + kh * 8;

    floatx4 acc = {0.f, 0.f, 0.f, 0.f};
    #pragma unroll
    for (int k = 0; k < NFEAT; k += 32) {
        short8 a = *(const short8*)(A + k);
        short8 b = *(const short8*)(B + k);
        acc = __builtin_amdgcn_mfma_f32_16x16x32_bf16(a, b, acc, 0, 0, 0);
    }
    const int col = n0 + lr;                 // C/D: col = lane&15
    const float bias = bp[col];
    const int rbase = m0 + kh * 4;           // C/D: row = (lane>>4)*4 + r
    #pragma unroll
    for (int r = 0; r < 4; ++r) {
        int row = rbase + r;
        float x = acc[r] + bias * pres[row];
        x = (x > 0.0f) ? x : (__expf(x) - 1.0f);   // elu
        ctx[(size_t)row * NFEAT + col] = f2b(x);
    }
}

// -------- Kernel 2b: GRU cell, fused GEMMs + gates -> out[G,256] fp32 --------
__global__ void __launch_bounds__(256)
k2b_gru(const u16* __restrict__ ctx, const u16* __restrict__ gfb,
        const float* __restrict__ gf,
        const u16* __restrict__ Wih, const u16* __restrict__ Whh,
        const float* __restrict__ bih, const float* __restrict__ bhh,
        float* __restrict__ out)
{
    const int t = threadIdx.x;
    const int wid = blockIdx.x * 4 + (t >> 6);
    const int lane = t & 63;
    const int m0 = (wid >> 4) * 16;
    const int j0 = (wid & 15) * 16;
    const int lr = lane & 15;
    const int kh = lane >> 4;

    const short* A1 = (const short*)ctx + (size_t)(m0 + lr) * NFEAT + kh * 8;
    const short* A2 = (const short*)gfb + (size_t)(m0 + lr) * NFEAT + kh * 8;
    const size_t boff = (size_t)(j0 + lr) * NFEAT + kh * 8;
    const short* Bir = (const short*)Wih + boff;
    const short* Biz = Bir + 256 * NFEAT;
    const short* Bin = Bir + 512 * NFEAT;
    const short* Bhr = (const short*)Whh + boff;
    const short* Bhz = Bhr + 256 * NFEAT;
    const short* Bhn = Bhr + 512 * NFEAT;

    floatx4 air = {0,0,0,0}, aiz = {0,0,0,0}, ain = {0,0,0,0};
    floatx4 ahr = {0,0,0,0}, ahz = {0,0,0,0}, ahn = {0,0,0,0};
    #pragma unroll
    for (int k = 0; k < NFEAT; k += 32) {
        short8 a1 = *(const short8*)(A1 + k);
        short8 a2 = *(const short8*)(A2 + k);
        air = __builtin_amdgcn_mfma_f32_16x16x32_bf16(a1, *(const short8*)(Bir + k), air, 0, 0, 0);
        aiz = __builtin_amdgcn_mfma_f32_16x16x32_bf16(a1, *(const short8*)(Biz + k), aiz, 0, 0, 0);
        ain = __builtin_amdgcn_mfma_f32_16x16x32_bf16(a1, *(const short8*)(Bin + k), ain, 0, 0, 0);
        ahr = __builtin_amdgcn_mfma_f32_16x16x32_bf16(a2, *(const short8*)(Bhr + k), ahr, 0, 0, 0);
        ahz = __builtin_amdgcn_mfma_f32_16x16x32_bf16(a2, *(const short8*)(Bhz + k), ahz, 0, 0, 0);
        ahn = __builtin_amdgcn_mfma_f32_16x16x32_bf16(a2, *(const short8*)(Bhn + k), ahn, 0, 0, 0);
    }
    const int col = j0 + lr;
    const float b_ir = bih[col], b_iz = bih[256 + col], b_in = bih[512 + col];
    const float b_hr = bhh[col], b_hz = bhh[256 + col], b_hn = bhh[512 + col];
    const int rbase = m0 + kh * 4;
    #pragma unroll
    for (int r = 0; r < 4; ++r) {
        int row = rbase + r;
        float rg = sigmoidf_((air[r] + b_ir) + (ahr[r] + b_hr));
        float ug = sigmoidf_((aiz[r] + b_iz) + (ahz[r] + b_hz));
        float ng = tanhf((ain[r] + b_in) + rg * (ahn[r] + b_hn));
        float h  = gf[(size_t)row * NFEAT + col];   // fp32 hidden state
        out[(size_t)row * NFEAT + col] = (1.0f - ug) * ng + ug * h;
    }
}

extern "C" void kernel_launch(void* const* d_in, const int* in_sizes, int n_in,
                              void* d_out, int out_size, void* d_ws, size_t ws_size,
                              hipStream_t stream)
{
    const float* nf  = (const float*)d_in[0];   // node_feats [V,256] fp32
    const float* gf  = (const float*)d_in[1];   // g_feats   [G,256] fp32
    const int*   seg = (const int*)d_in[2];     // segment_ids [V], sorted
    const float* Wl  = (const float*)d_in[3];   // [1,512]
    const float* bl  = (const float*)d_in[4];   // [1]
    const float* Wp  = (const float*)d_in[5];   // [256,256]
    const float* bp  = (const float*)d_in[6];   // [256]
    const float* Wih = (const float*)d_in[7];   // [768,256]
    const float* Whh = (const float*)d_in[8];   // [768,256]
    const float* bih = (const float*)d_in[9];   // [768]
    const float* bhh = (const float*)d_in[10];  // [768]

    const int V = in_sizes[2];
    const int G = in_sizes[1] / NFEAT;

    // workspace layout (16B-aligned regions)
    char* ws = (char*)d_ws;
    u16*   sbuf = (u16*)ws;                           ws += (size_t)G * NFEAT * 2;  // 2 MB
    u16*   ctx  = (u16*)ws;                           ws += (size_t)G * NFEAT * 2;  // 2 MB
    u16*   gfb  = (u16*)ws;                           ws += (size_t)G * NFEAT * 2;  // 2 MB
    u16*   wpb  = (u16*)ws;                           ws += (size_t)256 * 256 * 2;  // 128 KB
    u16*   wihb = (u16*)ws;                           ws += (size_t)768 * 256 * 2;  // 384 KB
    u16*   whhb = (u16*)ws;                           ws += (size_t)768 * 256 * 2;  // 384 KB
    float* pres = (float*)ws;                         ws += (size_t)G * 4;          // 16 KB

    k1_attn_pool<<<G, 256, 0, stream>>>(nf, gf, seg, Wl, bl, Wp, Wih, Whh,
                                        sbuf, pres, gfb, wpb, wihb, whhb, V);
    k2a_project<<<G / 4, 256, 0, stream>>>(sbuf, wpb, bp, pres, ctx);
    k2b_gru<<<G / 4, 256, 0, stream>>>(ctx, gfb, gf, wihb, whhb, bih, bhh, (float*)d_out);
    (void)ws_size; (void)n_in; (void)out_size;
}

// Round 4
// 427.131 us; speedup vs baseline: 1.0846x; 1.0257x over previous
//
#include <hip/hip_runtime.h>
#include <hip/hip_bf16.h>
#include <stdint.h>

typedef unsigned short u16;
typedef __attribute__((ext_vector_type(8))) short short8;
typedef __attribute__((ext_vector_type(4))) float floatx4;

#define NFEAT 256

__device__ __forceinline__ unsigned short f2b(float f) {
    unsigned int x = __builtin_bit_cast(unsigned int, f);
    x += 0x7fffu + ((x >> 16) & 1u);   // round-to-nearest-even
    return (unsigned short)(x >> 16);
}
__device__ __forceinline__ float sigmoidf_(float x) {
    return 1.0f / (1.0f + __expf(-x));
}

// -------- Kernel 1: single-pass online-softmax attention pooling --------
// fp32 in -> s[G,256] bf16, pres[G]. Each wave processes 2 rows/iter with a
// depth-2 prefetch (2 KB in flight/wave); one shared rescale per row pair.
// Also converts Wp / W_ih / W_hh / g_feats to bf16 workspace copies for k2.
__global__ void __launch_bounds__(256)
k1_attn_pool(const float* __restrict__ nf, const float* __restrict__ gf,
             const int* __restrict__ seg, const float* __restrict__ Wl,
             const float* __restrict__ bl,
             const float* __restrict__ Wp, const float* __restrict__ Wih,
             const float* __restrict__ Whh,
             u16* __restrict__ s_out,
             float* __restrict__ pres, u16* __restrict__ gfb,
             u16* __restrict__ wpb, u16* __restrict__ wihb, u16* __restrict__ whhb,
             int V)
{
    const int g = blockIdx.x;
    const int t = threadIdx.x;
    __shared__ float red[256];
    __shared__ float accs[4][256];
    __shared__ float mws[4], lws[4];

    // ---- fold-in: bf16 conversion of weights (1M threads cover 458752 elems) ----
    {
        const int n1 = 256 * 256;            // Wp
        const int n2 = n1 + 768 * 256;       // + W_ih
        const int n3 = n2 + 768 * 256;       // + W_hh
        int idx = g * 256 + t;
        if (idx < n3) {
            if (idx < n1)       wpb[idx]       = f2b(Wp[idx]);
            else if (idx < n2)  wihb[idx - n1] = f2b(Wih[idx - n1]);
            else                whhb[idx - n2] = f2b(Whh[idx - n2]);
        }
    }

    // ---- g_feats row g: bf16 copy (raw) + graph-uniform logit part (relu'd) ----
    const float gfv = gf[(size_t)g * NFEAT + t];
    gfb[(size_t)g * NFEAT + t] = f2b(gfv);
    red[t] = fmaxf(gfv, 0.0f) * Wl[t];
    __syncthreads();
    #pragma unroll
    for (int off = 128; off > 0; off >>= 1) {
        if (t < off) red[t] += red[t + off];
        __syncthreads();
    }
    const float gbase = red[0] + bl[0];
    __syncthreads();

    // ---- segment bounds [start, start+count) by binary search on sorted ids ----
    int lo = 0, hi = V;
    while (lo < hi) { int mid = (lo + hi) >> 1; if (seg[mid] < g) lo = mid + 1; else hi = mid; }
    const int start = lo;
    hi = V;
    while (lo < hi) { int mid = (lo + hi) >> 1; if (seg[mid] <= g) lo = mid + 1; else hi = mid; }
    const int count = lo - start;

    const int lane = t & 63;
    const int wv = t >> 6;

    // node-half Wl coefficients, 4 per lane
    const float4 wn = *(const float4*)(Wl + NFEAT + lane * 4);

    // ---- single pass: online softmax + weighted accumulation, 2 rows/iter ----
    float m = -3.0e38f, l = 0.0f;
    float4 acc = {0.f, 0.f, 0.f, 0.f};
    const float* base = nf + (size_t)start * NFEAT + lane * 4;

    float4 x0 = {0.f,0.f,0.f,0.f}, x1 = {0.f,0.f,0.f,0.f};
    {
        int i = wv * 2;
        if (i < count)     x0 = *(const float4*)(base + (size_t)i * NFEAT);
        if (i + 1 < count) x1 = *(const float4*)(base + (size_t)(i + 1) * NFEAT);
    }
    for (int i = wv * 2; i < count; i += 8) {
        float4 p0v = {0.f,0.f,0.f,0.f}, p1v = {0.f,0.f,0.f,0.f};
        if (i + 8 < count) p0v = *(const float4*)(base + (size_t)(i + 8) * NFEAT);
        if (i + 9 < count) p1v = *(const float4*)(base + (size_t)(i + 9) * NFEAT);

        float d0 = x0.x * wn.x + x0.y * wn.y + x0.z * wn.z + x0.w * wn.w;
        float d1 = x1.x * wn.x + x1.y * wn.y + x1.z * wn.z + x1.w * wn.w;
        #pragma unroll
        for (int off = 32; off > 0; off >>= 1) {
            d0 += __shfl_xor(d0, off);
            d1 += __shfl_xor(d1, off);
        }
        float z0 = d0 + gbase; z0 = (z0 > 0.0f) ? z0 : 0.01f * z0;
        float z1 = d1 + gbase; z1 = (z1 > 0.0f) ? z1 : 0.01f * z1;
        if (i + 1 >= count) z1 = -3.0e38f;      // row1 invalid -> weight 0

        float mn = fmaxf(m, fmaxf(z0, z1));
        float c  = __expf(m - mn);
        float p0 = __expf(z0 - mn);
        float p1 = __expf(z1 - mn);
        l = l * c + p0 + p1;
        acc.x = acc.x * c + p0 * x0.x + p1 * x1.x;
        acc.y = acc.y * c + p0 * x0.y + p1 * x1.y;
        acc.z = acc.z * c + p0 * x0.z + p1 * x1.z;
        acc.w = acc.w * c + p0 * x0.w + p1 * x1.w;
        m = mn;
        x0 = p0v; x1 = p1v;
    }

    // ---- merge the 4 waves' (m, l, acc) ----
    accs[wv][lane * 4 + 0] = acc.x;
    accs[wv][lane * 4 + 1] = acc.y;
    accs[wv][lane * 4 + 2] = acc.z;
    accs[wv][lane * 4 + 3] = acc.w;
    if (lane == 0) { mws[wv] = m; lws[wv] = l; }
    __syncthreads();

    const float M = fmaxf(fmaxf(mws[0], mws[1]), fmaxf(mws[2], mws[3]));
    const float c0 = __expf(mws[0] - M), c1 = __expf(mws[1] - M);
    const float c2 = __expf(mws[2] - M), c3 = __expf(mws[3] - M);
    const float L = lws[0] * c0 + lws[1] * c1 + lws[2] * c2 + lws[3] * c3;
    const float sv = accs[0][t] * c0 + accs[1][t] * c1 + accs[2][t] * c2 + accs[3][t] * c3;
    const float inv = (L > 0.0f) ? 1.0f / L : 0.0f;   // count==0 -> s=0
    s_out[(size_t)g * NFEAT + t] = f2b(sv * inv);
    if (t == 0) pres[g] = (count > 0) ? 1.0f : 0.0f;
}

// -------- Kernel 2 (fused): context projection + elu + GRU cell --------
// One block per 16-graph stripe (512 thr = 8 waves). Phase A: waves compute
// ctx = elu(s@Wp^T + bp*pres) into LDS (padded stride). Phase B: GRU GEMMs
// with A-fragments (ctx from LDS, gfb from global) loaded once per wave.
#define CTX_LD 264   // 16-row LDS ctx, row stride 264 u16 (528 B) to break banks
__global__ void __launch_bounds__(512)
k2_fused(const u16* __restrict__ s, const u16* __restrict__ wpb,
         const float* __restrict__ bp, const float* __restrict__ pres,
         const u16* __restrict__ gfb, const float* __restrict__ gf,
         const u16* __restrict__ wihb, const u16* __restrict__ whhb,
         const float* __restrict__ bih, const float* __restrict__ bhh,
         float* __restrict__ out)
{
    __shared__ u16 ctx[16][CTX_LD];
    const int t = threadIdx.x;
    const int w = t >> 6;            // wave 0..7
    const int lane = t & 63;
    const int m0 = blockIdx.x * 16;  // graph-row stripe
    const int lr = lane & 15;
    const int kh = lane >> 4;

    // ---- phase A: wave w computes ctx col-tiles {2w, 2w+1} ----
    {
        const short* A = (const short*)s + (size_t)(m0 + lr) * NFEAT + kh * 8;
        short8 af[8];
        #pragma unroll
        for (int kk = 0; kk < 8; ++kk) af[kk] = *(const short8*)(A + kk * 32);

        #pragma unroll
        for (int nt = 0; nt < 2; ++nt) {
            const int n0 = (w * 2 + nt) * 16;
            const short* B = (const short*)wpb + (size_t)(n0 + lr) * NFEAT + kh * 8;
            floatx4 acc = {0.f, 0.f, 0.f, 0.f};
            #pragma unroll
            for (int kk = 0; kk < 8; ++kk)
                acc = __builtin_amdgcn_mfma_f32_16x16x32_bf16(af[kk], *(const short8*)(B + kk * 32), acc, 0, 0, 0);
            const int col = n0 + lr;
            const float bias = bp[col];
            #pragma unroll
            for (int r = 0; r < 4; ++r) {
                int rl = kh * 4 + r;                    // local row
                float x = acc[r] + bias * pres[m0 + rl];
                x = (x > 0.0f) ? x : (__expf(x) - 1.0f);  // elu
                ctx[rl][col] = f2b(x);
            }
        }
    }
    __syncthreads();

    // ---- phase B: wave w handles out col-tiles {2w, 2w+1} ----
    short8 a1[8], a2[8];
    #pragma unroll
    for (int kk = 0; kk < 8; ++kk)
        a1[kk] = *(const short8*)&ctx[lr][kk * 32 + kh * 8];
    {
        const short* A2 = (const short*)gfb + (size_t)(m0 + lr) * NFEAT + kh * 8;
        #pragma unroll
        for (int kk = 0; kk < 8; ++kk) a2[kk] = *(const short8*)(A2 + kk * 32);
    }

    #pragma unroll
    for (int jt = 0; jt < 2; ++jt) {
        const int j0 = (w * 2 + jt) * 16;
        const size_t boff = (size_t)(j0 + lr) * NFEAT + kh * 8;
        const short* Bir = (const short*)wihb + boff;
        const short* Biz = Bir + 256 * NFEAT;
        const short* Bin = Bir + 512 * NFEAT;
        const short* Bhr = (const short*)whhb + boff;
        const short* Bhz = Bhr + 256 * NFEAT;
        const short* Bhn = Bhr + 512 * NFEAT;

        floatx4 air = {0,0,0,0}, aiz = {0,0,0,0}, ain = {0,0,0,0};
        floatx4 ahr = {0,0,0,0}, ahz = {0,0,0,0}, ahn = {0,0,0,0};
        #pragma unroll
        for (int kk = 0; kk < 8; ++kk) {
            const int k = kk * 32;
            air = __builtin_amdgcn_mfma_f32_16x16x32_bf16(a1[kk], *(const short8*)(Bir + k), air, 0, 0, 0);
            aiz = __builtin_amdgcn_mfma_f32_16x16x32_bf16(a1[kk], *(const short8*)(Biz + k), aiz, 0, 0, 0);
            ain = __builtin_amdgcn_mfma_f32_16x16x32_bf16(a1[kk], *(const short8*)(Bin + k), ain, 0, 0, 0);
            ahr = __builtin_amdgcn_mfma_f32_16x16x32_bf16(a2[kk], *(const short8*)(Bhr + k), ahr, 0, 0, 0);
            ahz = __builtin_amdgcn_mfma_f32_16x16x32_bf16(a2[kk], *(const short8*)(Bhz + k), ahz, 0, 0, 0);
            ahn = __builtin_amdgcn_mfma_f32_16x16x32_bf16(a2[kk], *(const short8*)(Bhn + k), ahn, 0, 0, 0);
        }
        const int col = j0 + lr;
        const float b_ir = bih[col], b_iz = bih[256 + col], b_in = bih[512 + col];
        const float b_hr = bhh[col], b_hz = bhh[256 + col], b_hn = bhh[512 + col];
        #pragma unroll
        for (int r = 0; r < 4; ++r) {
            int row = m0 + kh * 4 + r;
            float rg = sigmoidf_((air[r] + b_ir) + (ahr[r] + b_hr));
            float ug = sigmoidf_((aiz[r] + b_iz) + (ahz[r] + b_hz));
            float ng = tanhf((ain[r] + b_in) + rg * (ahn[r] + b_hn));
            float h  = gf[(size_t)row * NFEAT + col];   // fp32 hidden state
            out[(size_t)row * NFEAT + col] = (1.0f - ug) * ng + ug * h;
        }
    }
}

extern "C" void kernel_launch(void* const* d_in, const int* in_sizes, int n_in,
                              void* d_out, int out_size, void* d_ws, size_t ws_size,
                              hipStream_t stream)
{
    const float* nf  = (const float*)d_in[0];   // node_feats [V,256] fp32
    const float* gf  = (const float*)d_in[1];   // g_feats   [G,256] fp32
    const int*   seg = (const int*)d_in[2];     // segment_ids [V], sorted
    const float* Wl  = (const float*)d_in[3];   // [1,512]
    const float* bl  = (const float*)d_in[4];   // [1]
    const float* Wp  = (const float*)d_in[5];   // [256,256]
    const float* bp  = (const float*)d_in[6];   // [256]
    const float* Wih = (const float*)d_in[7];   // [768,256]
    const float* Whh = (const float*)d_in[8];   // [768,256]
    const float* bih = (const float*)d_in[9];   // [768]
    const float* bhh = (const float*)d_in[10];  // [768]

    const int V = in_sizes[2];
    const int G = in_sizes[1] / NFEAT;

    // workspace layout (16B-aligned regions)
    char* ws = (char*)d_ws;
    u16*   sbuf = (u16*)ws;                           ws += (size_t)G * NFEAT * 2;  // 2 MB
    u16*   gfb  = (u16*)ws;                           ws += (size_t)G * NFEAT * 2;  // 2 MB
    u16*   wpb  = (u16*)ws;                           ws += (size_t)256 * 256 * 2;  // 128 KB
    u16*   wihb = (u16*)ws;                           ws += (size_t)768 * 256 * 2;  // 384 KB
    u16*   whhb = (u16*)ws;                           ws += (size_t)768 * 256 * 2;  // 384 KB
    float* pres = (float*)ws;                         ws += (size_t)G * 4;          // 16 KB

    k1_attn_pool<<<G, 256, 0, stream>>>(nf, gf, seg, Wl, bl, Wp, Wih, Whh,
                                        sbuf, pres, gfb, wpb, wihb, whhb, V);
    k2_fused<<<G / 16, 512, 0, stream>>>(sbuf, wpb, bp, pres, gfb, gf,
                                         wihb, whhb, bih, bhh, (float*)d_out);
    (void)ws_size; (void)n_in; (void)out_size;
}